// Round 1
// baseline (703.447 us; speedup 1.0000x reference)
//
#include <hip/hip_runtime.h>
#include <cstdint>
#include <cstddef>

// Problem constants (Learnable_32650341384420)
#define HH 1024      // H (channels)
#define LL 8192      // L (sequence)
#define NB 4         // B (batch)
#define KD 64
#define KLEN 512     // KD * 2^(NS-1)

typedef float v4f __attribute__((ext_vector_type(4)));
typedef short v8s __attribute__((ext_vector_type(8)));

__device__ __forceinline__ unsigned short f2bf(float f) {
  union { float f; unsigned int u; } x; x.f = f;
  unsigned int r = x.u + 0x7fffu + ((x.u >> 16) & 1u);
  return (unsigned short)(r >> 16);
}

// ---------------------------------------------------------------------------
// K1: build normalized 512-tap kernel per h (fp32).
// Replicates F.interpolate(linear, align_corners=False) + scale + sum + L2 norm.
// ---------------------------------------------------------------------------
__global__ __launch_bounds__(512) void build_k_kernel(
    const float* __restrict__ k0, const float* __restrict__ k1,
    const float* __restrict__ k2, const float* __restrict__ k3,
    float* __restrict__ kout) {
  __shared__ float lk[4][KD];
  __shared__ float red[512];
  const int h = blockIdx.x;
  const int t = threadIdx.x;
  if (t < 256) {
    int i = t >> 6, j = t & 63;
    const float* src = (i == 0) ? k0 : (i == 1) ? k1 : (i == 2) ? k2 : k3;
    lk[i][j] = src[h * KD + j];
  }
  __syncthreads();
  float kt = 0.f;
#pragma unroll
  for (int i = 0; i < 4; i++) {
    int len = KD << i;
    if (t < len) {
      float inv = 1.0f / (float)(1 << i);          // scale = 2^i
      float c = ((float)t + 0.5f) * inv - 0.5f;    // half-pixel coord
      c = fminf(fmaxf(c, 0.0f), 63.0f);
      int lo = (int)floorf(c);
      int hi = min(lo + 1, 63);
      float w = c - (float)lo;
      float v = lk[i][lo] * (1.0f - w) + lk[i][hi] * w;
      kt += v * (float)(1 << (3 - i));             // part scale 8,4,2,1
    }
  }
  red[t] = kt * kt;
  __syncthreads();
  for (int s = 256; s > 0; s >>= 1) {
    if (t < s) red[t] += red[t + s];
    __syncthreads();
  }
  float norm = sqrtf(red[0]);
  kout[h * KLEN + t] = kt / norm;
}

// ---------------------------------------------------------------------------
// K2: W (fp32 [1024][1024]) -> bf16 bits
// ---------------------------------------------------------------------------
__global__ void w2bf_kernel(const float* __restrict__ W,
                            unsigned short* __restrict__ Wb, int n) {
  int i = blockIdx.x * blockDim.x + threadIdx.x;
  if (i < n) Wb[i] = f2bf(W[i]);
}

// ---------------------------------------------------------------------------
// K3: depthwise causal 512-tap FIR + D*u + exact gelu -> g bf16 [b][h][l]
// One block per (b,h) row. 512 threads, 16 outputs/thread, 32-reg sliding
// window: per 16-tap chunk -> 256 FMAs vs 8 LDS b128 reads.
// ---------------------------------------------------------------------------
__global__ __launch_bounds__(512) void conv_kernel(
    const float* __restrict__ u, const float* __restrict__ kk,
    const float* __restrict__ D, unsigned short* __restrict__ g) {
  __shared__ __align__(16) float su[KLEN + LL];  // [0,512)=0 pad, then u row
  __shared__ __align__(16) float sk[KLEN];
  const int bid = blockIdx.x;
  const int h = bid & (HH - 1);
  const int b = bid >> 10;
  const int tid = threadIdx.x;

  const float* urow = u + (size_t)(b * HH + h) * LL;
  su[tid] = 0.f;  // tid < 512 == KLEN: zero causal pad
  {
    const float4* u4 = (const float4*)urow;
    float4* s4 = (float4*)(su + KLEN);
#pragma unroll
    for (int i = 0; i < 4; i++) s4[tid + i * 512] = u4[tid + i * 512];
  }
  if (tid < KLEN / 4) ((float4*)sk)[tid] = ((const float4*)(kk + h * KLEN))[tid];
  __syncthreads();

  const int l0 = tid * 16;
  float acc[16];
#pragma unroll
  for (int j = 0; j < 16; j++) acc[j] = 0.f;

  // window invariant at chunk tc: w[x] = su[496 + l0 - 16*tc + x], x in [0,32)
  float w[32];
#pragma unroll
  for (int i = 0; i < 8; i++) {
    float4 t4 = *(const float4*)&su[496 + l0 + i * 4];
    w[i * 4 + 0] = t4.x; w[i * 4 + 1] = t4.y;
    w[i * 4 + 2] = t4.z; w[i * 4 + 3] = t4.w;
  }
  const float4* sk4 = (const float4*)sk;
  for (int tc = 0; tc < 32; tc++) {
#pragma unroll
    for (int si = 0; si < 4; si++) {
      float4 kq = sk4[tc * 4 + si];
      const int s0 = si * 4;
#pragma unroll
      for (int j = 0; j < 16; j++) acc[j] = fmaf(kq.x, w[16 + j - s0], acc[j]);
#pragma unroll
      for (int j = 0; j < 16; j++) acc[j] = fmaf(kq.y, w[15 + j - s0], acc[j]);
#pragma unroll
      for (int j = 0; j < 16; j++) acc[j] = fmaf(kq.z, w[14 + j - s0], acc[j]);
#pragma unroll
      for (int j = 0; j < 16; j++) acc[j] = fmaf(kq.w, w[13 + j - s0], acc[j]);
    }
    if (tc < 31) {
#pragma unroll
      for (int x = 0; x < 16; x++) w[16 + x] = w[x];
#pragma unroll
      for (int i = 0; i < 4; i++) {
        float4 t4 = *(const float4*)&su[480 + l0 - tc * 16 + i * 4];
        w[i * 4 + 0] = t4.x; w[i * 4 + 1] = t4.y;
        w[i * 4 + 2] = t4.z; w[i * 4 + 3] = t4.w;
      }
    }
  }

  const float Dh = D[h];
  unsigned short hb[16];
#pragma unroll
  for (int j = 0; j < 16; j++) {
    float y = acc[j] + Dh * su[KLEN + l0 + j];
    float ge = 0.5f * y * (1.0f + erff(y * 0.70710678118654752f));
    hb[j] = f2bf(ge);
  }
  uint4 o0v, o1v;
  o0v.x = (unsigned)hb[0]  | ((unsigned)hb[1]  << 16);
  o0v.y = (unsigned)hb[2]  | ((unsigned)hb[3]  << 16);
  o0v.z = (unsigned)hb[4]  | ((unsigned)hb[5]  << 16);
  o0v.w = (unsigned)hb[6]  | ((unsigned)hb[7]  << 16);
  o1v.x = (unsigned)hb[8]  | ((unsigned)hb[9]  << 16);
  o1v.y = (unsigned)hb[10] | ((unsigned)hb[11] << 16);
  o1v.z = (unsigned)hb[12] | ((unsigned)hb[13] << 16);
  o1v.w = (unsigned)hb[14] | ((unsigned)hb[15] << 16);
  uint4* gp = (uint4*)(g + (size_t)(b * HH + h) * LL + l0);
  gp[0] = o0v;
  gp[1] = o1v;
}

// ---------------------------------------------------------------------------
// K4: transpose g[b][h][l] -> g_t[b][l][h] (bf16), 64x64 LDS tiles
// ---------------------------------------------------------------------------
__global__ __launch_bounds__(256) void transpose_kernel(
    const unsigned short* __restrict__ g, unsigned short* __restrict__ gt) {
  __shared__ unsigned short s[64][65];
  const int bid = blockIdx.x;
  const int lc = bid & 127;
  const int hc = (bid >> 7) & 15;
  const int b = bid >> 11;
  const int l0 = lc * 64, h0 = hc * 64;
  const int tid = threadIdx.x;
  const int seg = tid & 7, rr = tid >> 3;  // seg: 8-elem column group, rr: 0..31
#pragma unroll
  for (int p = 0; p < 2; p++) {
    int r = p * 32 + rr;
    uint4 v = *(const uint4*)(g + (size_t)(b * HH + h0 + r) * LL + l0 + seg * 8);
    s[r][seg * 8 + 0] = (unsigned short)(v.x);
    s[r][seg * 8 + 1] = (unsigned short)(v.x >> 16);
    s[r][seg * 8 + 2] = (unsigned short)(v.y);
    s[r][seg * 8 + 3] = (unsigned short)(v.y >> 16);
    s[r][seg * 8 + 4] = (unsigned short)(v.z);
    s[r][seg * 8 + 5] = (unsigned short)(v.z >> 16);
    s[r][seg * 8 + 6] = (unsigned short)(v.w);
    s[r][seg * 8 + 7] = (unsigned short)(v.w >> 16);
  }
  __syncthreads();
#pragma unroll
  for (int p = 0; p < 2; p++) {
    int lr = p * 32 + rr;
    unsigned int a0 = (unsigned)s[seg * 8 + 0][lr] | ((unsigned)s[seg * 8 + 1][lr] << 16);
    unsigned int a1 = (unsigned)s[seg * 8 + 2][lr] | ((unsigned)s[seg * 8 + 3][lr] << 16);
    unsigned int a2 = (unsigned)s[seg * 8 + 4][lr] | ((unsigned)s[seg * 8 + 5][lr] << 16);
    unsigned int a3 = (unsigned)s[seg * 8 + 6][lr] | ((unsigned)s[seg * 8 + 7][lr] << 16);
    uint4 ov; ov.x = a0; ov.y = a1; ov.z = a2; ov.w = a3;
    *(uint4*)(gt + (size_t)(b * LL + l0 + lr) * HH + h0 + seg * 8) = ov;
  }
}

// ---------------------------------------------------------------------------
// K5: GEMM out[b][o][l] = sum_h W[o][h] * g_t[b*L+l][h] + bias[o]
// m97-style gemm_bt: both operands K-contiguous, global_load_lds width=16,
// 128x128 tile, BK=32, 4 waves each 64x64 (4x4 of 16x16x32 bf16 MFMA).
// ---------------------------------------------------------------------------
__device__ __forceinline__ void gll16(const void* g, void* l) {
  __builtin_amdgcn_global_load_lds(
      (const __attribute__((address_space(1))) unsigned int*)g,
      (__attribute__((address_space(3))) unsigned int*)l, 16, 0, 0);
}

__global__ __launch_bounds__(256) void gemm_kernel(
    const unsigned short* __restrict__ A,   // W bf16 [1024][1024] (o-major, k=h contig)
    const unsigned short* __restrict__ Bt,  // g_t bf16 [32768][1024] (n-major, k contig)
    const float* __restrict__ bias, float* __restrict__ out) {
  __shared__ __align__(16) unsigned short sA[128 * 32];  // [m][k], row=64B
  __shared__ __align__(16) unsigned short sB[128 * 32];  // [n][k]
  const int tid = threadIdx.x;
  const int wv = tid >> 6, ln = tid & 63;
  const int bid = blockIdx.x;
  const int mt = bid & 7, nt = bid >> 3;
  const int o0 = mt * 128, n0 = nt * 128;
  const int m16 = ln & 15, q4 = ln >> 4;
  const int wm = wv & 1, wn = wv >> 1;

  v4f acc[4][4];
#pragma unroll
  for (int i = 0; i < 4; i++)
#pragma unroll
    for (int j = 0; j < 4; j++) {
      v4f z = {0.f, 0.f, 0.f, 0.f};
      acc[i][j] = z;
    }

  // staging: 16 chunks of 1024B (64 lanes x 16B); chunk c = wv*4+q
  const unsigned short* gptr[4];
  unsigned short* lptr[4];
#pragma unroll
  for (int q = 0; q < 4; q++) {
    int c = wv * 4 + q;
    int rr = (c & 7) * 16 + (ln >> 2);
    int cc = (ln & 3) * 8;
    if (c < 8) { gptr[q] = A  + (size_t)(o0 + rr) * HH + cc; lptr[q] = sA + c * 512; }
    else       { gptr[q] = Bt + (size_t)(n0 + rr) * HH + cc; lptr[q] = sB + (c - 8) * 512; }
  }

  for (int kk = 0; kk < 32; kk++) {
    const int k0 = kk * 32;
#pragma unroll
    for (int q = 0; q < 4; q++) gll16(gptr[q] + k0, lptr[q]);
    __syncthreads();
    v8s af[4], bf4[4];
#pragma unroll
    for (int i = 0; i < 4; i++)
      af[i] = *(const v8s*)&sA[(wm * 64 + i * 16 + m16) * 32 + q4 * 8];
#pragma unroll
    for (int i = 0; i < 4; i++)
      bf4[i] = *(const v8s*)&sB[(wn * 64 + i * 16 + m16) * 32 + q4 * 8];
#pragma unroll
    for (int i = 0; i < 4; i++)
#pragma unroll
      for (int j = 0; j < 4; j++)
        acc[i][j] = __builtin_amdgcn_mfma_f32_16x16x32_bf16(af[i], bf4[j], acc[i][j], 0, 0, 0);
    __syncthreads();
  }

  // epilogue: D row = q4*4+reg (m), col = m16 (n)  [verified m89/m91 mapping]
#pragma unroll
  for (int i = 0; i < 4; i++) {
    const int ob = o0 + wm * 64 + i * 16 + q4 * 4;
#pragma unroll
    for (int j = 0; j < 4; j++) {
      const int n = n0 + wn * 64 + j * 16 + m16;
      const int bb = n >> 13;
      const int l = n & (LL - 1);
#pragma unroll
      for (int r = 0; r < 4; r++) {
        const int o = ob + r;
        out[(size_t)(bb * HH + o) * LL + l] = acc[i][j][r] + bias[o];
      }
    }
  }
}

// ---------------------------------------------------------------------------
extern "C" void kernel_launch(void* const* d_in, const int* in_sizes, int n_in,
                              void* d_out, int out_size, void* d_ws, size_t ws_size,
                              hipStream_t stream) {
  const float* u   = (const float*)d_in[0];
  const float* k0  = (const float*)d_in[1];
  const float* k1  = (const float*)d_in[2];
  const float* k2  = (const float*)d_in[3];
  const float* k3  = (const float*)d_in[4];
  const float* D   = (const float*)d_in[5];
  const float* W   = (const float*)d_in[6];
  const float* bia = (const float*)d_in[7];
  float* out = (float*)d_out;

  // ws layout: g_t (64 MiB) | k fp32 (2 MiB) | W bf16 (2 MiB)  => 68 MiB
  char* ws = (char*)d_ws;
  unsigned short* gt = (unsigned short*)ws;
  float* kws         = (float*)(ws + (size_t)67108864);
  unsigned short* Wb = (unsigned short*)(ws + (size_t)69206016);
  // g (bf16, 64 MiB) lives in d_out's buffer as scratch; K5 overwrites all of d_out.
  unsigned short* g = (unsigned short*)d_out;

  build_k_kernel<<<HH, 512, 0, stream>>>(k0, k1, k2, k3, kws);
  w2bf_kernel<<<(HH * HH + 255) / 256, 256, 0, stream>>>(W, Wb, HH * HH);
  conv_kernel<<<NB * HH, 512, 0, stream>>>(u, kws, D, g);
  transpose_kernel<<<NB * 16 * 128, 256, 0, stream>>>(g, gt);
  gemm_kernel<<<8 * 256, 256, 0, stream>>>(Wb, gt, bia, out);
}

// Round 2
// 401.139 us; speedup vs baseline: 1.7536x; 1.7536x over previous
//
#include <hip/hip_runtime.h>
#include <cstdint>
#include <cstddef>

// Problem constants (Learnable_32650341384420)
#define HH 1024      // H (channels)
#define LL 8192      // L (sequence)
#define NB 4         // B (batch)
#define KD 64
#define KLEN 512     // KD * 2^(NS-1)

typedef float v4f  __attribute__((ext_vector_type(4)));
typedef float v16f __attribute__((ext_vector_type(16)));
typedef short v8s  __attribute__((ext_vector_type(8)));

__device__ __forceinline__ unsigned short f2bf(float f) {
  union { float f; unsigned int u; } x; x.f = f;
  unsigned int r = x.u + 0x7fffu + ((x.u >> 16) & 1u);
  return (unsigned short)(r >> 16);
}

// ---------------------------------------------------------------------------
// K1: build normalized 512-tap kernel per h (fp32).
// ---------------------------------------------------------------------------
__global__ __launch_bounds__(512) void build_k_kernel(
    const float* __restrict__ k0, const float* __restrict__ k1,
    const float* __restrict__ k2, const float* __restrict__ k3,
    float* __restrict__ kout) {
  __shared__ float lk[4][KD];
  __shared__ float red[512];
  const int h = blockIdx.x;
  const int t = threadIdx.x;
  if (t < 256) {
    int i = t >> 6, j = t & 63;
    const float* src = (i == 0) ? k0 : (i == 1) ? k1 : (i == 2) ? k2 : k3;
    lk[i][j] = src[h * KD + j];
  }
  __syncthreads();
  float kt = 0.f;
#pragma unroll
  for (int i = 0; i < 4; i++) {
    int len = KD << i;
    if (t < len) {
      float inv = 1.0f / (float)(1 << i);
      float c = ((float)t + 0.5f) * inv - 0.5f;
      c = fminf(fmaxf(c, 0.0f), 63.0f);
      int lo = (int)floorf(c);
      int hi = min(lo + 1, 63);
      float w = c - (float)lo;
      float v = lk[i][lo] * (1.0f - w) + lk[i][hi] * w;
      kt += v * (float)(1 << (3 - i));
    }
  }
  red[t] = kt * kt;
  __syncthreads();
  for (int s = 256; s > 0; s >>= 1) {
    if (t < s) red[t] += red[t + s];
    __syncthreads();
  }
  float norm = sqrtf(red[0]);
  kout[h * KLEN + t] = kt / norm;
}

// ---------------------------------------------------------------------------
// K2: W (fp32) -> bf16 bits
// ---------------------------------------------------------------------------
__global__ void w2bf_kernel(const float* __restrict__ W,
                            unsigned short* __restrict__ Wb, int n) {
  int i = blockIdx.x * blockDim.x + threadIdx.x;
  if (i < n) Wb[i] = f2bf(W[i]);
}

// ---------------------------------------------------------------------------
// K3 v2: depthwise causal 512-tap FIR via block-Toeplitz MFMA.
// y[32I+j] = sum_a K_a[j][c] u[32(I-a)+c],  K_a[j][c] = k[32a+j-c]  (a<17)
// One block per h. A = 32x544 Toeplitz band, fragment-packed in LDS.
// B = u row staged to LDS as bf16 (512-elt zero left-pad).
// 4 waves x 2 tiles (32x32 outputs each), 34 mfma_f32_32x32x16_bf16 per tile.
// Epilogue: +D*u (fp32 from global) + exact gelu -> g bf16 [b][h][l].
// ---------------------------------------------------------------------------
__global__ __launch_bounds__(256) void conv_kernel(
    const float* __restrict__ u, const float* __restrict__ kk,
    const float* __restrict__ D, unsigned short* __restrict__ g) {
  __shared__ __align__(16) unsigned short Apk[34 * 512];  // fragment-packed A
  __shared__ __align__(16) unsigned short su[512 + LL];   // bf16 u row, left pad
  __shared__ __align__(16) float skk[KLEN];               // fp32 k row

  const int h = blockIdx.x;
  const int tid = threadIdx.x;
  const int w = tid >> 6;
  const int ln = tid & 63;
  const int n = ln & 31;        // MFMA col (block index i)
  const int q = ln >> 5;        // k-half selector

  // stage normalized kernel row
  if (tid < 128) *(float4*)(skk + tid * 4) = *(const float4*)(kk + (size_t)h * KLEN + tid * 4);
  __syncthreads();

  // build fragment-packed Toeplitz A: Apk[s*512 + lane*8 + j] = A[m][16s+q*8+j]
  // m=lane&31, q=lane>>5; a=s>>1; c=(s&1)*16+q*8+j; t=32a+m-c
#pragma unroll 4
  for (int e = 0; e < 68; ++e) {
    int idx = e * 256 + tid;
    int s = idx >> 9;
    int lane = (idx >> 3) & 63;
    int j = idx & 7;
    int m = lane & 31, q2 = lane >> 5;
    int c = ((s & 1) << 4) + (q2 << 3) + j;
    int t = ((s >> 1) << 5) + m - c;
    Apk[idx] = (t >= 0 && t < KLEN) ? f2bf(skk[t]) : (unsigned short)0;
  }

  const float Dh = D[h];
  const int b_base0 = 512 + 32 * (w * 64 + n) + 8 * q;  // tile0: i0 = 64w
  const int b_base1 = b_base0 + 1024;                   // tile1: i0 = 64w+32

  for (int b = 0; b < NB; ++b) {
    __syncthreads();  // prev-iter su readers done (and Apk built, iter 0)
    const float* __restrict__ urow = u + ((size_t)b * HH + h) * LL;
    if (tid < 64) {
      uint4 z; z.x = 0; z.y = 0; z.z = 0; z.w = 0;
      *(uint4*)(su + tid * 8) = z;
    }
#pragma unroll
    for (int r = 0; r < 8; ++r) {
      int i = r * 1024 + tid * 4;
      float4 v = *(const float4*)(urow + i);
      uint2 p;
      p.x = (unsigned)f2bf(v.x) | ((unsigned)f2bf(v.y) << 16);
      p.y = (unsigned)f2bf(v.z) | ((unsigned)f2bf(v.w) << 16);
      *(uint2*)(su + 512 + i) = p;
    }
    __syncthreads();

    v16f acc0, acc1;
#pragma unroll
    for (int r = 0; r < 16; ++r) { acc0[r] = 0.f; acc1[r] = 0.f; }

#pragma unroll
    for (int s = 0; s < 34; ++s) {
      const int off = ((s & 1) << 4) - ((s >> 1) << 5);
      v8s af = *(const v8s*)(Apk + (s << 9) + (ln << 3));
      v8s b0 = *(const v8s*)(su + b_base0 + off);
      v8s b1 = *(const v8s*)(su + b_base1 + off);
      acc0 = __builtin_amdgcn_mfma_f32_32x32x16_bf16(af, b0, acc0, 0, 0, 0);
      acc1 = __builtin_amdgcn_mfma_f32_32x32x16_bf16(af, b1, acc1, 0, 0, 0);
    }

    // epilogue: C layout col=n, row=(reg&3)+8*(reg>>2)+4*q
    unsigned short* grow = g + ((size_t)b * HH + h) * LL;
#pragma unroll
    for (int t = 0; t < 2; ++t) {
      const int i0 = w * 64 + t * 32;
#pragma unroll
      for (int rg = 0; rg < 4; ++rg) {
        const int l = 32 * (i0 + n) + 8 * rg + 4 * q;
        float4 uu = *(const float4*)(urow + l);
        const float* up = (const float*)&uu;
        unsigned short hb[4];
#pragma unroll
        for (int rr = 0; rr < 4; ++rr) {
          float y = (t ? acc1[rg * 4 + rr] : acc0[rg * 4 + rr]) + Dh * up[rr];
          float ge = 0.5f * y * (1.0f + erff(y * 0.70710678118654752f));
          hb[rr] = f2bf(ge);
        }
        uint2 p;
        p.x = (unsigned)hb[0] | ((unsigned)hb[1] << 16);
        p.y = (unsigned)hb[2] | ((unsigned)hb[3] << 16);
        *(uint2*)(grow + l) = p;
      }
    }
  }
}

// ---------------------------------------------------------------------------
// K4: transpose g[b][h][l] -> g_t[b][l][h] (bf16), 64x64 LDS tiles
// ---------------------------------------------------------------------------
__global__ __launch_bounds__(256) void transpose_kernel(
    const unsigned short* __restrict__ g, unsigned short* __restrict__ gt) {
  __shared__ unsigned short s[64][65];
  const int bid = blockIdx.x;
  const int lc = bid & 127;
  const int hc = (bid >> 7) & 15;
  const int b = bid >> 11;
  const int l0 = lc * 64, h0 = hc * 64;
  const int tid = threadIdx.x;
  const int seg = tid & 7, rr = tid >> 3;
#pragma unroll
  for (int p = 0; p < 2; p++) {
    int r = p * 32 + rr;
    uint4 v = *(const uint4*)(g + (size_t)(b * HH + h0 + r) * LL + l0 + seg * 8);
    s[r][seg * 8 + 0] = (unsigned short)(v.x);
    s[r][seg * 8 + 1] = (unsigned short)(v.x >> 16);
    s[r][seg * 8 + 2] = (unsigned short)(v.y);
    s[r][seg * 8 + 3] = (unsigned short)(v.y >> 16);
    s[r][seg * 8 + 4] = (unsigned short)(v.z);
    s[r][seg * 8 + 5] = (unsigned short)(v.z >> 16);
    s[r][seg * 8 + 6] = (unsigned short)(v.w);
    s[r][seg * 8 + 7] = (unsigned short)(v.w >> 16);
  }
  __syncthreads();
#pragma unroll
  for (int p = 0; p < 2; p++) {
    int lr = p * 32 + rr;
    unsigned int a0 = (unsigned)s[seg * 8 + 0][lr] | ((unsigned)s[seg * 8 + 1][lr] << 16);
    unsigned int a1 = (unsigned)s[seg * 8 + 2][lr] | ((unsigned)s[seg * 8 + 3][lr] << 16);
    unsigned int a2 = (unsigned)s[seg * 8 + 4][lr] | ((unsigned)s[seg * 8 + 5][lr] << 16);
    unsigned int a3 = (unsigned)s[seg * 8 + 6][lr] | ((unsigned)s[seg * 8 + 7][lr] << 16);
    uint4 ov; ov.x = a0; ov.y = a1; ov.z = a2; ov.w = a3;
    *(uint4*)(gt + (size_t)(b * LL + l0 + lr) * HH + h0 + seg * 8) = ov;
  }
}

// ---------------------------------------------------------------------------
// K5: GEMM out[b][o][l] = sum_h W[o][h] * g_t[b*L+l][h] + bias[o]
// ---------------------------------------------------------------------------
__device__ __forceinline__ void gll16(const void* g, void* l) {
  __builtin_amdgcn_global_load_lds(
      (const __attribute__((address_space(1))) unsigned int*)g,
      (__attribute__((address_space(3))) unsigned int*)l, 16, 0, 0);
}

__global__ __launch_bounds__(256) void gemm_kernel(
    const unsigned short* __restrict__ A,   // W bf16 [1024][1024]
    const unsigned short* __restrict__ Bt,  // g_t bf16 [32768][1024]
    const float* __restrict__ bias, float* __restrict__ out) {
  __shared__ __align__(16) unsigned short sA[128 * 32];
  __shared__ __align__(16) unsigned short sB[128 * 32];
  const int tid = threadIdx.x;
  const int wv = tid >> 6, ln = tid & 63;
  const int bid = blockIdx.x;
  const int mt = bid & 7, nt = bid >> 3;
  const int o0 = mt * 128, n0 = nt * 128;
  const int m16 = ln & 15, q4 = ln >> 4;
  const int wm = wv & 1, wn = wv >> 1;

  v4f acc[4][4];
#pragma unroll
  for (int i = 0; i < 4; i++)
#pragma unroll
    for (int j = 0; j < 4; j++) {
      v4f z = {0.f, 0.f, 0.f, 0.f};
      acc[i][j] = z;
    }

  const unsigned short* gptr[4];
  unsigned short* lptr[4];
#pragma unroll
  for (int qq = 0; qq < 4; qq++) {
    int c = wv * 4 + qq;
    int rr = (c & 7) * 16 + (ln >> 2);
    int cc = (ln & 3) * 8;
    if (c < 8) { gptr[qq] = A  + (size_t)(o0 + rr) * HH + cc; lptr[qq] = sA + c * 512; }
    else       { gptr[qq] = Bt + (size_t)(n0 + rr) * HH + cc; lptr[qq] = sB + (c - 8) * 512; }
  }

  for (int kk = 0; kk < 32; kk++) {
    const int k0 = kk * 32;
#pragma unroll
    for (int qq = 0; qq < 4; qq++) gll16(gptr[qq] + k0, lptr[qq]);
    __syncthreads();
    v8s af[4], bf4[4];
#pragma unroll
    for (int i = 0; i < 4; i++)
      af[i] = *(const v8s*)&sA[(wm * 64 + i * 16 + m16) * 32 + q4 * 8];
#pragma unroll
    for (int i = 0; i < 4; i++)
      bf4[i] = *(const v8s*)&sB[(wn * 64 + i * 16 + m16) * 32 + q4 * 8];
#pragma unroll
    for (int i = 0; i < 4; i++)
#pragma unroll
      for (int j = 0; j < 4; j++)
        acc[i][j] = __builtin_amdgcn_mfma_f32_16x16x32_bf16(af[i], bf4[j], acc[i][j], 0, 0, 0);
    __syncthreads();
  }

#pragma unroll
  for (int i = 0; i < 4; i++) {
    const int ob = o0 + wm * 64 + i * 16 + q4 * 4;
#pragma unroll
    for (int j = 0; j < 4; j++) {
      const int nn = n0 + wn * 64 + j * 16 + m16;
      const int bb = nn >> 13;
      const int l = nn & (LL - 1);
#pragma unroll
      for (int r = 0; r < 4; r++) {
        const int o = ob + r;
        out[(size_t)(bb * HH + o) * LL + l] = acc[i][j][r] + bias[o];
      }
    }
  }
}

// ---------------------------------------------------------------------------
extern "C" void kernel_launch(void* const* d_in, const int* in_sizes, int n_in,
                              void* d_out, int out_size, void* d_ws, size_t ws_size,
                              hipStream_t stream) {
  const float* u   = (const float*)d_in[0];
  const float* k0  = (const float*)d_in[1];
  const float* k1  = (const float*)d_in[2];
  const float* k2  = (const float*)d_in[3];
  const float* k3  = (const float*)d_in[4];
  const float* D   = (const float*)d_in[5];
  const float* W   = (const float*)d_in[6];
  const float* bia = (const float*)d_in[7];
  float* out = (float*)d_out;

  // ws layout: g_t (64 MiB) | k fp32 (2 MiB) | W bf16 (2 MiB)
  char* ws = (char*)d_ws;
  unsigned short* gt = (unsigned short*)ws;
  float* kws         = (float*)(ws + (size_t)67108864);
  unsigned short* Wb = (unsigned short*)(ws + (size_t)69206016);
  unsigned short* g = (unsigned short*)d_out;  // scratch in d_out

  build_k_kernel<<<HH, 512, 0, stream>>>(k0, k1, k2, k3, kws);
  w2bf_kernel<<<(HH * HH + 255) / 256, 256, 0, stream>>>(W, Wb, HH * HH);
  conv_kernel<<<HH, 256, 0, stream>>>(u, kws, D, g);
  transpose_kernel<<<NB * 16 * 128, 256, 0, stream>>>(g, gt);
  gemm_kernel<<<8 * 256, 256, 0, stream>>>(Wb, gt, bia, out);
}